// Round 1
// baseline (96.162 us; speedup 1.0000x reference)
//
#include <hip/hip_runtime.h>
#include <math.h>

#define N_AGENTS 1024
#define HIDDEN   128
#define GRIDSZ   32
#define NCELLS   1024   // 32*32
#define KDIM     2048

// K1: Sh[j][c'] = sum over d with ((d>>3)&3)==c' of hidden[j][d]
__global__ __launch_bounds__(256) void k_sh(const float* __restrict__ hidden,
                                            float* __restrict__ Sh) {
    int t = blockIdx.x * 256 + threadIdx.x;   // 4096 threads
    if (t >= N_AGENTS * 4) return;
    int j = t >> 2, c = t & 3;
    const float* h = hidden + j * HIDDEN + c * 8;
    float s = 0.f;
#pragma unroll
    for (int u = 0; u < 4; ++u)
#pragma unroll
        for (int e = 0; e < 8; ++e)
            s += h[u * 32 + e];
    Sh[t] = s;
}

// K2: per agent i, compute cell winners (last-j-wins == max j) then the 2048-wide
// pooled grid row via the Sh table.
__global__ __launch_bounds__(256) void k_grid(const float* __restrict__ obs2,
                                              const float* __restrict__ Sh,
                                              float* __restrict__ G) {
    __shared__ int win[NCELLS];
    __shared__ float sx[N_AGENTS], sy[N_AGENTS];
    int i = blockIdx.x;
    int tid = threadIdx.x;
    for (int c = tid; c < NCELLS; c += 256) win[c] = -1;
    for (int j = tid; j < N_AGENTS; j += 256) {
        sx[j] = obs2[2 * j];
        sy[j] = obs2[2 * j + 1];
    }
    __syncthreads();
    float xi = sx[i], yi = sy[i];
    if (!isnan(xi)) {
        for (int j = tid; j < N_AGENTS; j += 256) {
            if (j == i) continue;
            float xj = sx[j], yj = sy[j];
            if (isnan(xj)) continue;
            // exact match of reference fp32 math: /0.125 == *8 (exact), then +16
            float rx = (xj - xi) * 8.0f + 16.0f;
            float ry = (yj - yi) * 8.0f + 16.0f;
            if (rx >= 0.0f && rx < 32.0f && ry >= 0.0f && ry < 32.0f) {
                int c = (int)rx * GRIDSZ + (int)ry;   // trunc == floor on [0,32)
                atomicMax(&win[c], j);
            }
        }
    }
    __syncthreads();
    float* Gr = G + (size_t)i * KDIM;
    for (int g = tid; g < KDIM; g += 256) {
        int p = g >> 2, cp = g & 3;
        int w0 = win[2 * p], w1 = win[2 * p + 1];
        float v = 0.f;
        if (w0 >= 0) v += Sh[w0 * 4 + cp];
        if (w1 >= 0) v += Sh[w1 * 4 + cp];
        Gr[g] = v;
    }
}

// K0: out[i][h] = b[h]
__global__ __launch_bounds__(256) void k_bias(const float* __restrict__ b,
                                              float* __restrict__ out) {
    int t = blockIdx.x * 256 + threadIdx.x;   // 131072 threads
    out[t] = b[t & (HIDDEN - 1)];
}

// K3: split-K GEMM: out(1024x128) += G(1024x2048) @ W^T.  grid=(32 m-tiles, 8 k-splits)
#define BK 16
__global__ __launch_bounds__(256) void k_gemm(const float* __restrict__ G,
                                              const float* __restrict__ W,
                                              float* __restrict__ out) {
    __shared__ float Gs[32][BK];
    __shared__ float Ws[BK][HIDDEN];
    int i0 = blockIdx.x * 32;       // M tile base
    int k0 = blockIdx.y * 256;      // K chunk base
    int tid = threadIdx.x;
    int lane = tid & 63;
    int wave = tid >> 6;
    int m0 = wave * 8;              // wave handles 8 rows
    int n = lane * 2;               // lane handles 2 consecutive cols
    float acc[8][2] = {};
    for (int kc = 0; kc < 256; kc += BK) {
        int kb = k0 + kc;
        // Gs: 32x16 = 512 elems, 2/thread, 16-float contiguous runs
        {
            int idx = tid;
#pragma unroll
            for (int r = 0; r < 2; ++r, idx += 256) {
                int m = idx >> 4, kk = idx & 15;
                Gs[m][kk] = G[(size_t)(i0 + m) * KDIM + kb + kk];
            }
        }
        // Ws[kk][n] = W[n][kb+kk]: 16x128 elems, 8/thread contiguous in k
        {
            int base = tid * 8;
            int nn = base >> 4;
            int kk0 = base & 15;
#pragma unroll
            for (int s = 0; s < 8; ++s)
                Ws[kk0 + s][nn] = W[(size_t)nn * KDIM + kb + kk0 + s];
        }
        __syncthreads();
#pragma unroll
        for (int kk = 0; kk < BK; ++kk) {
            float w0 = Ws[kk][n], w1 = Ws[kk][n + 1];   // stride-2 lanes: conflict-free
#pragma unroll
            for (int m = 0; m < 8; ++m) {
                float gm = Gs[m0 + m][kk];              // wave-uniform: broadcast
                acc[m][0] += gm * w0;
                acc[m][1] += gm * w1;
            }
        }
        __syncthreads();
    }
#pragma unroll
    for (int m = 0; m < 8; ++m) {
        float* o = out + (size_t)(i0 + m0 + m) * HIDDEN + n;
        atomicAdd(&o[0], acc[m][0]);
        atomicAdd(&o[1], acc[m][1]);
    }
}

extern "C" void kernel_launch(void* const* d_in, const int* in_sizes, int n_in,
                              void* d_out, int out_size, void* d_ws, size_t ws_size,
                              hipStream_t stream) {
    const float* hidden = (const float*)d_in[0];
    // d_in[1] = obs1 — unused by the reference
    const float* obs2   = (const float*)d_in[2];
    const float* W      = (const float*)d_in[3];
    const float* b      = (const float*)d_in[4];
    float* out = (float*)d_out;

    float* Sh = (float*)d_ws;                          // 1024*4 floats = 16 KB
    float* G  = (float*)((char*)d_ws + 16384);         // 1024*2048 floats = 8 MB

    k_sh  <<<16,   256, 0, stream>>>(hidden, Sh);
    k_grid<<<1024, 256, 0, stream>>>(obs2, Sh, G);
    k_bias<<<512,  256, 0, stream>>>(b, out);
    k_gemm<<<dim3(32, 8), 256, 0, stream>>>(G, W, out);
}

// Round 2
// 88.755 us; speedup vs baseline: 1.0835x; 1.0835x over previous
//
#include <hip/hip_runtime.h>
#include <math.h>

#define N_AGENTS 1024
#define HIDDEN   128
#define GRIDSZ   32
#define NCELLS   1024   // 32*32
#define KDIM     2048
#define NSPLIT   16
#define KCHUNK   (KDIM / NSPLIT)   // 128
#define BK       16

// K1: Sh[j][c'] = sum over d with ((d>>3)&3)==c' of hidden[j][d]  (j-major, 4 per agent)
__global__ __launch_bounds__(256) void k_sh(const float* __restrict__ hidden,
                                            float* __restrict__ Sh) {
    int t = blockIdx.x * 256 + threadIdx.x;   // 4096 threads
    int j = t >> 2, c = t & 3;
    const float* h = hidden + j * HIDDEN + c * 8;
    float s = 0.f;
#pragma unroll
    for (int u = 0; u < 4; ++u) {
        float4 a = *(const float4*)(h + u * 32);
        float4 b = *(const float4*)(h + u * 32 + 4);
        s += a.x + a.y + a.z + a.w + b.x + b.y + b.z + b.w;
    }
    Sh[t] = s;
}

// K2: per agent i: cell winners (last-j-wins == max j) in LDS, then the pooled
// 2048-wide grid row, vectorized: 4 consecutive g share one cell pair.
__global__ __launch_bounds__(256) void k_grid(const float* __restrict__ obs2,
                                              const float4* __restrict__ Sh4,
                                              float4* __restrict__ G4) {
    __shared__ int win[NCELLS];
    __shared__ float2 spos[N_AGENTS];
    __shared__ float4 ssh[N_AGENTS];
    int i = blockIdx.x;
    int tid = threadIdx.x;
    for (int c = tid; c < NCELLS; c += 256) win[c] = -1;
    const float2* o2 = (const float2*)obs2;
    for (int j = tid; j < N_AGENTS; j += 256) {
        spos[j] = o2[j];
        ssh[j] = Sh4[j];
    }
    __syncthreads();
    float2 pi = spos[i];
    if (!isnan(pi.x)) {
        for (int j = tid; j < N_AGENTS; j += 256) {
            float2 pj = spos[j];
            if (j == i || isnan(pj.x)) continue;
            // exact reference fp32 math: /0.125 == *8 (exact pow2), then +16
            float rx = (pj.x - pi.x) * 8.0f + 16.0f;
            float ry = (pj.y - pi.y) * 8.0f + 16.0f;
            if (rx >= 0.0f && rx < 32.0f && ry >= 0.0f && ry < 32.0f)
                atomicMax(&win[(int)rx * GRIDSZ + (int)ry], j);  // trunc == floor on [0,32)
        }
    }
    __syncthreads();
    float4* Gr = G4 + (size_t)i * (KDIM / 4);
    for (int p = tid; p < KDIM / 4; p += 256) {   // 2 iters
        int w0 = win[2 * p], w1 = win[2 * p + 1];
        float4 v = {0.f, 0.f, 0.f, 0.f};
        if (w0 >= 0) { float4 a = ssh[w0]; v.x += a.x; v.y += a.y; v.z += a.z; v.w += a.w; }
        if (w1 >= 0) { float4 a = ssh[w1]; v.x += a.x; v.y += a.y; v.z += a.z; v.w += a.w; }
        Gr[p] = v;
    }
}

// K3: split-K GEMM partials: part[y][i][h] = G(i, kchunk_y) @ W^T(kchunk_y, h)
// half-wave lane owns 4 n (b128 W-tile read) x 4 m rows -> 16 FMA per 5 LDS instrs.
__global__ __launch_bounds__(256) void k_gemm(const float* __restrict__ G,
                                              const float* __restrict__ W,
                                              float* __restrict__ part) {
    __shared__ float Gs[32][BK];
    __shared__ float Ws[BK][HIDDEN];
    int i0 = blockIdx.x * 32;
    int k0 = blockIdx.y * KCHUNK;
    int tid = threadIdx.x;
    int lane5 = tid & 31;           // n-chunk: cols 4*lane5 .. +3
    int mrow = (tid >> 5) * 4;      // 8 half-waves x 4 rows = 32 rows
    float acc[4][4] = {};
    for (int kc = 0; kc < KCHUNK; kc += BK) {
        int kb = k0 + kc;
        if (tid < 128) {            // Gs: 32x16 floats, one float4 per thread
            int m = tid >> 2, q = tid & 3;
            float4 g = *(const float4*)(G + (size_t)(i0 + m) * KDIM + kb + q * 4);
            *(float4*)&Gs[m][q * 4] = g;
        }
        {                           // Ws[kk][n] = W[n][kb+kk], transposed staging
            int n = tid >> 1, kk0 = (tid & 1) * 8;
            const float* wp = W + (size_t)n * KDIM + kb + kk0;
            float4 a = *(const float4*)wp;
            float4 bfour = *(const float4*)(wp + 4);
            Ws[kk0 + 0][n] = a.x; Ws[kk0 + 1][n] = a.y;
            Ws[kk0 + 2][n] = a.z; Ws[kk0 + 3][n] = a.w;
            Ws[kk0 + 4][n] = bfour.x; Ws[kk0 + 5][n] = bfour.y;
            Ws[kk0 + 6][n] = bfour.z; Ws[kk0 + 7][n] = bfour.w;
        }
        __syncthreads();
#pragma unroll
        for (int kk = 0; kk < BK; ++kk) {
            float4 wv = *(const float4*)&Ws[kk][lane5 * 4];
#pragma unroll
            for (int m = 0; m < 4; ++m) {
                float gm = Gs[mrow + m][kk];    // half-wave-uniform: broadcast
                acc[m][0] += gm * wv.x;
                acc[m][1] += gm * wv.y;
                acc[m][2] += gm * wv.z;
                acc[m][3] += gm * wv.w;
            }
        }
        __syncthreads();
    }
#pragma unroll
    for (int m = 0; m < 4; ++m) {
        float* o = part + ((size_t)blockIdx.y * N_AGENTS + i0 + mrow + m) * HIDDEN + lane5 * 4;
        *(float4*)o = *(float4*)acc[m];
    }
}

// K4: out[i][h] = b[h] + sum_y part[y][i][h]   (float4 per thread, deterministic)
__global__ __launch_bounds__(256) void k_reduce(const float* __restrict__ part,
                                                const float* __restrict__ bias,
                                                float* __restrict__ out) {
    int t = blockIdx.x * 256 + threadIdx.x;   // 32768 threads
    int h4 = t & (HIDDEN / 4 - 1);
    float4 s = ((const float4*)bias)[h4];
    const float4* p4 = (const float4*)part;
#pragma unroll
    for (int y = 0; y < NSPLIT; ++y) {
        float4 a = p4[(size_t)y * (N_AGENTS * HIDDEN / 4) + t];
        s.x += a.x; s.y += a.y; s.z += a.z; s.w += a.w;
    }
    ((float4*)out)[t] = s;
}

extern "C" void kernel_launch(void* const* d_in, const int* in_sizes, int n_in,
                              void* d_out, int out_size, void* d_ws, size_t ws_size,
                              hipStream_t stream) {
    const float* hidden = (const float*)d_in[0];
    // d_in[1] = obs1 — unused by the reference
    const float* obs2   = (const float*)d_in[2];
    const float* W      = (const float*)d_in[3];
    const float* b      = (const float*)d_in[4];
    float* out = (float*)d_out;

    float* Sh   = (float*)d_ws;                               // 16 KB
    float* G    = (float*)((char*)d_ws + 16384);              // 8 MB
    float* part = (float*)((char*)d_ws + 16384 + 8388608);    // NSPLIT * 512 KB = 8 MB

    k_sh    <<<16,            256, 0, stream>>>(hidden, Sh);
    k_grid  <<<1024,          256, 0, stream>>>(obs2, (const float4*)Sh, (float4*)G);
    k_gemm  <<<dim3(32, NSPLIT), 256, 0, stream>>>(G, W, part);
    k_reduce<<<128,           256, 0, stream>>>(part, b, out);
}